// Round 6
// baseline (740.968 us; speedup 1.0000x reference)
//
#include <hip/hip_runtime.h>
#include <hip/hip_bf16.h>
#include <math.h>

// RWKV-7 TimeMix. R9: wkv7 streams z,b,k,r packed to bf16 pairs (zb16, kr16)
// -> 3x ds_read_b128 + 1x b32 per step (was 5+1); v back in LDS (revert R8's
// v-reg-prefetch); w (decay) and v stay fp32. kkprep restructured to 4
// cols/lane, emits packed buffers coalesced + fp32 kout for gn.
// Keeps R8's fusion: s2-g GEMM + v_first copy ride in the wkv7 launch.
// B=4 T=2048 C=768 H=12 N=64, LAYER_ID=1.

#define B_  4
#define T_  2048
#define C_  768
#define H_  12

typedef __attribute__((ext_vector_type(8))) short bf16x8;
typedef __attribute__((ext_vector_type(4))) float f32x4;

#define GLD16(gsrc, ldst)                                                     \
  __builtin_amdgcn_global_load_lds(                                           \
      (const __attribute__((address_space(1))) void*)(gsrc),                  \
      (__attribute__((address_space(3))) void*)(ldst), 16, 0, 0)

// ---- DPP helpers: sum across each 16-lane DPP row, all-VALU ----
template <int CTRL>
static __device__ __forceinline__ float row_ror_add(float v) {
  int t = __builtin_amdgcn_update_dpp(0, __float_as_int(v), CTRL, 0xF, 0xF, true);
  return v + __int_as_float(t);
}
static __device__ __forceinline__ float row_sum16(float v) {
  v = row_ror_add<0x128>(v);  // row_ror:8
  v = row_ror_add<0x124>(v);  // row_ror:4
  v = row_ror_add<0x122>(v);  // row_ror:2
  v = row_ror_add<0x121>(v);  // row_ror:1
  return v;
}

static __device__ __forceinline__ float wave_sum64(float v) {
  v = row_sum16(v);
  v += __shfl_xor(v, 16);
  v += __shfl_xor(v, 32);
  return v;
}

static __device__ __forceinline__ short bf16b(float f) {
  __hip_bfloat16 h = __float2bfloat16(f);
  return *reinterpret_cast<short*>(&h);
}

static __device__ __forceinline__ float bf2f(short s) {
  const unsigned u = ((unsigned)(unsigned short)s) << 16;
  return __int_as_float((int)u);
}

enum { EPI_NONE = 0, EPI_TANH, EPI_WDECAY, EPI_SIGBIAS, EPI_SIGMOID, EPI_VMIX };

static __device__ __forceinline__ float apply_epi_f(int epi, float val, int n,
                                                    int gmrow, int N,
                                                    const float* bias,
                                                    const float* ex1,
                                                    const float* ex2) {
  if (epi == EPI_TANH) {
    val = tanhf(val);
  } else if (epi == EPI_WDECAY) {
    const float u = bias[n] + val;
    const float sig = 1.f / (1.f + expf(-u));
    val = expf(-0.60653065971263342f * sig);
  } else if (epi == EPI_SIGBIAS) {
    const float u = bias[n] + val;
    val = 1.f / (1.f + expf(-u));
  } else if (epi == EPI_SIGMOID) {
    val = 1.f / (1.f + expf(-val));
  } else if (epi == EPI_VMIX) {
    const float u = bias[n] + val;
    const float sg = 1.f / (1.f + expf(-u));
    const size_t off = (size_t)gmrow * N + n;
    const float v0v = ex1[off];
    const float vf = ex2[off];
    val = v0v + (vf - v0v) * sg;
  }
  return val;
}

// ---------------- bf16 MFMA GEMM tile bodies ----------------
static __device__ __forceinline__ void gemm128_tile(
    const short* __restrict__ A, const short* __restrict__ Bw,
    float* __restrict__ C, short* __restrict__ C16, int M, int N, int K,
    int bx, int by, int epi, const float* bias, const float* ex1,
    const float* ex2, short* As, short* Bs) {
  const int tid = threadIdx.x;
  const int wave = tid >> 6, lane = tid & 63;
  const int m0 = by * 128, n0 = bx * 128;
  const int wm = (wave >> 1) * 64, wn = (wave & 1) * 64;
  const int fr = lane & 15, fk = (lane >> 4) * 8;

  f32x4 acc[4][4];
#pragma unroll
  for (int i = 0; i < 4; i++)
#pragma unroll
    for (int j = 0; j < 4; j++) acc[i][j] = (f32x4){0.f, 0.f, 0.f, 0.f};

  const int srow = tid >> 2, scol = (tid & 3) * 8;
  const short* gA = A + (size_t)(m0 + srow) * K + scol;
  const short* gB = Bw + (size_t)(n0 + srow) * K + scol;
  short* lA0 = &As[wave * 512];
  short* lA1 = &As[2048 + wave * 512];
  short* lB0 = &Bs[wave * 512];
  short* lB1 = &Bs[2048 + wave * 512];

  for (int k0 = 0; k0 < K; k0 += 32) {
    GLD16(gA + k0, lA0);
    GLD16(gA + (size_t)64 * K + k0, lA1);
    GLD16(gB + k0, lB0);
    GLD16(gB + (size_t)64 * K + k0, lB1);
    __syncthreads();

    bf16x8 af[4], bf[4];
#pragma unroll
    for (int i = 0; i < 4; i++)
      af[i] = *(const bf16x8*)&As[(wm + i * 16 + fr) * 32 + fk];
#pragma unroll
    for (int j = 0; j < 4; j++)
      bf[j] = *(const bf16x8*)&Bs[(wn + j * 16 + fr) * 32 + fk];
#pragma unroll
    for (int i = 0; i < 4; i++)
#pragma unroll
      for (int j = 0; j < 4; j++)
        acc[i][j] =
            __builtin_amdgcn_mfma_f32_16x16x32_bf16(af[i], bf[j], acc[i][j], 0, 0, 0);
    __syncthreads();
  }

  // C/D layout: col = lane&15, row = (lane>>4)*4 + reg  [m89/m91 verified]
#pragma unroll
  for (int i = 0; i < 4; i++) {
    const int gm = m0 + wm + i * 16 + (lane >> 4) * 4;
#pragma unroll
    for (int j = 0; j < 4; j++) {
      const int gn = n0 + wn + j * 16 + fr;
#pragma unroll
      for (int rix = 0; rix < 4; rix++) {
        float val = acc[i][j][rix];
        val = apply_epi_f(epi, val, gn, gm + rix, N, bias, ex1, ex2);
        C[(size_t)(gm + rix) * N + gn] = val;
        if (C16) C16[(size_t)(gm + rix) * N + gn] = bf16b(val);
      }
    }
  }
}

static __device__ __forceinline__ void gemm64_tile(
    const short* __restrict__ A, const short* __restrict__ Bw,
    short* __restrict__ out16, int M, int N, int K, int bx, int by, int epi,
    short* As, short* Bs) {
  const int tid = threadIdx.x;
  const int wave = tid >> 6, lane = tid & 63;
  const int m0 = by * 128, n0 = bx * 64;
  const int wm = (wave >> 1) * 64, wn = (wave & 1) * 32;
  const int fr = lane & 15, fk = (lane >> 4) * 8;

  f32x4 acc[4][2];
#pragma unroll
  for (int i = 0; i < 4; i++)
#pragma unroll
    for (int j = 0; j < 2; j++) acc[i][j] = (f32x4){0.f, 0.f, 0.f, 0.f};

  const int srow = tid >> 2, scol = (tid & 3) * 8;
  const short* gA = A + (size_t)(m0 + srow) * K + scol;
  const short* gB = Bw + (size_t)(n0 + srow) * K + scol;
  short* lA0 = &As[wave * 512];
  short* lA1 = &As[2048 + wave * 512];
  short* lB0 = &Bs[wave * 512];

  for (int k0 = 0; k0 < K; k0 += 32) {
    GLD16(gA + k0, lA0);
    GLD16(gA + (size_t)64 * K + k0, lA1);
    GLD16(gB + k0, lB0);
    __syncthreads();

    bf16x8 af[4], bf[2];
#pragma unroll
    for (int i = 0; i < 4; i++)
      af[i] = *(const bf16x8*)&As[(wm + i * 16 + fr) * 32 + fk];
#pragma unroll
    for (int j = 0; j < 2; j++)
      bf[j] = *(const bf16x8*)&Bs[(wn + j * 16 + fr) * 32 + fk];
#pragma unroll
    for (int i = 0; i < 4; i++)
#pragma unroll
      for (int j = 0; j < 2; j++)
        acc[i][j] =
            __builtin_amdgcn_mfma_f32_16x16x32_bf16(af[i], bf[j], acc[i][j], 0, 0, 0);
    __syncthreads();
  }

#pragma unroll
  for (int i = 0; i < 4; i++) {
    const int gm = m0 + wm + i * 16 + (lane >> 4) * 4;
#pragma unroll
    for (int j = 0; j < 2; j++) {
      const int gn = n0 + wn + j * 16 + fr;
#pragma unroll
      for (int rix = 0; rix < 4; rix++) {
        float val = acc[i][j][rix];
        if (epi == EPI_TANH) val = tanhf(val);
        else if (epi == EPI_SIGMOID) val = 1.f / (1.f + expf(-val));
        out16[(size_t)(gm + rix) * N + gn] = bf16b(val);
      }
    }
  }
}

// ---------------- merged GEMM kernels ----------------
__global__ __launch_bounds__(256) void big3_k(
    const short* __restrict__ xr, const short* __restrict__ xk,
    const short* __restrict__ xv, const short* __restrict__ wrb,
    const short* __restrict__ wkb, const short* __restrict__ wvb,
    float* __restrict__ r_, float* __restrict__ kbuf,
    float* __restrict__ vbuf, short* __restrict__ vbuf16) {
  __shared__ short smem[2 * 128 * 32];
  const int role = blockIdx.x / 6, bx = blockIdx.x % 6;
  const short* A;
  const short* Bw;
  float* C;
  short* C16 = nullptr;
  if (role == 0) { A = xr; Bw = wrb; C = r_; }
  else if (role == 1) { A = xk; Bw = wkb; C = kbuf; }
  else { A = xv; Bw = wvb; C = vbuf; C16 = vbuf16; }
  gemm128_tile(A, Bw, C, C16, B_ * T_, C_, C_, bx, blockIdx.y, EPI_NONE,
               nullptr, nullptr, nullptr, smem, smem + 128 * 32);
}

__global__ __launch_bounds__(256) void s1x4_k(
    const short* __restrict__ xw, const short* __restrict__ xa,
    const short* __restrict__ xg, const short* __restrict__ vbuf16,
    const short* __restrict__ wAT, const short* __restrict__ aAT,
    const short* __restrict__ gAT, const short* __restrict__ vAT,
    short* __restrict__ h_w, short* __restrict__ h_a,
    short* __restrict__ h_g, short* __restrict__ h_v) {
  __shared__ short smem[128 * 32 + 64 * 32];
  const int bx = blockIdx.x;  // 0..4
  const short* A;
  const short* Bw;
  short* O;
  int N, tb, epi;
  if (bx == 0)      { A = xw;     Bw = wAT; O = h_w; N = 64;  tb = 0; epi = EPI_TANH; }
  else if (bx == 1) { A = xa;     Bw = aAT; O = h_a; N = 64;  tb = 0; epi = EPI_NONE; }
  else if (bx == 2) { A = xg;     Bw = gAT; O = h_g; N = 128; tb = 0; epi = EPI_SIGMOID; }
  else if (bx == 3) { A = xg;     Bw = gAT; O = h_g; N = 128; tb = 1; epi = EPI_SIGMOID; }
  else              { A = vbuf16; Bw = vAT; O = h_v; N = 64;  tb = 0; epi = EPI_NONE; }
  gemm64_tile(A, Bw, O, B_ * T_, N, C_, tb, blockIdx.y, epi, smem,
              smem + 128 * 32);
}

__global__ __launch_bounds__(256) void s2x3_k(
    const short* __restrict__ h_v, const short* __restrict__ h_w,
    const short* __restrict__ h_a, const short* __restrict__ vBT,
    const short* __restrict__ wBT, const short* __restrict__ aBT,
    float* __restrict__ vbuf, float* __restrict__ dec_, float* __restrict__ a_,
    const float* __restrict__ v_miu, const float* __restrict__ w_miu,
    const float* __restrict__ a_miu, const float* __restrict__ v_first) {
  __shared__ short smem[2 * 128 * 32];
  const int role = blockIdx.x / 6, bx = blockIdx.x % 6;
  const short* A;
  const short* Bw;
  float* C;
  const float* bias;
  const float* ex1 = nullptr;
  const float* ex2 = nullptr;
  int epi;
  if (role == 0) { A = h_v; Bw = vBT; C = vbuf; bias = v_miu; ex1 = vbuf; ex2 = v_first; epi = EPI_VMIX; }
  else if (role == 1) { A = h_w; Bw = wBT; C = dec_; bias = w_miu; epi = EPI_WDECAY; }
  else { A = h_a; Bw = aBT; C = a_; bias = a_miu; epi = EPI_SIGBIAS; }
  gemm128_tile(A, Bw, C, nullptr, B_ * T_, C_, 64, bx, blockIdx.y, epi, bias,
               ex1, ex2, smem, smem + 128 * 32);
}

__global__ __launch_bounds__(256) void outp_k(
    const short* __restrict__ ymb, const short* __restrict__ wob,
    float* __restrict__ out) {
  __shared__ short smem[2 * 128 * 32];
  gemm128_tile(ymb, wob, out, nullptr, B_ * T_, C_, C_, blockIdx.x,
               blockIdx.y, EPI_NONE, nullptr, nullptr, nullptr, smem,
               smem + 128 * 32);
}

// ---------------- mix -> bf16 (6 lambdas, one pass) ----------------
__global__ __launch_bounds__(256) void mix6_k(
    const float* __restrict__ x, const float* __restrict__ lr,
    const float* __restrict__ lk, const float* __restrict__ lv,
    const float* __restrict__ lw, const float* __restrict__ la,
    const float* __restrict__ lg, short* __restrict__ xr,
    short* __restrict__ xk, short* __restrict__ xv, short* __restrict__ xw,
    short* __restrict__ xa, short* __restrict__ xg) {
  const int i = blockIdx.x * 256 + threadIdx.x;  // float4 index
  const int c4 = i % (C_ / 4);
  const int gm = i / (C_ / 4);
  const float4 xa4 = ((const float4*)x)[i];
  float4 xp = make_float4(0.f, 0.f, 0.f, 0.f);
  if ((gm % T_) != 0) xp = ((const float4*)x)[i - C_ / 4];
  const float4 dx =
      make_float4(xp.x - xa4.x, xp.y - xa4.y, xp.z - xa4.z, xp.w - xa4.w);

#define MIXOUT(dst, lam)                                                      \
  {                                                                           \
    const float4 l4 = ((const float4*)lam)[c4];                               \
    short4 o = {bf16b(fmaf(dx.x, l4.x, xa4.x)),                               \
                bf16b(fmaf(dx.y, l4.y, xa4.y)),                               \
                bf16b(fmaf(dx.z, l4.z, xa4.z)),                               \
                bf16b(fmaf(dx.w, l4.w, xa4.w))};                              \
    ((short4*)dst)[i] = o;                                                    \
  }
  MIXOUT(xr, lr);
  MIXOUT(xk, lk);
  MIXOUT(xv, lv);
  MIXOUT(xw, lw);
  MIXOUT(xa, la);
  MIXOUT(xg, lg);
#undef MIXOUT
}

// ------------- weights prep: 4 straight converts + 8 transposes ----------
__global__ __launch_bounds__(256) void wprep_k(
    const float* __restrict__ W_r, const float* __restrict__ W_k,
    const float* __restrict__ W_v, const float* __restrict__ W_o,
    const float* __restrict__ w_A, const float* __restrict__ a_A,
    const float* __restrict__ v_A, const float* __restrict__ g_A,
    const float* __restrict__ w_B, const float* __restrict__ a_B,
    const float* __restrict__ v_B, const float* __restrict__ g_B,
    short* __restrict__ wrb, short* __restrict__ wkb,
    short* __restrict__ wvb, short* __restrict__ wob,
    short* __restrict__ wAT, short* __restrict__ aAT,
    short* __restrict__ vAT, short* __restrict__ gAT,
    short* __restrict__ wBT, short* __restrict__ aBT,
    short* __restrict__ vBT, short* __restrict__ gBT) {
  const int job = blockIdx.y;
  const int WN = C_ * C_;
  if (job < 4) {
    const float* src = (job == 0) ? W_r : (job == 1) ? W_k : (job == 2) ? W_v : W_o;
    short* dst = (job == 0) ? wrb : (job == 1) ? wkb : (job == 2) ? wvb : wob;
    const int n4 = WN / 4;
    for (int i = blockIdx.x * 256 + threadIdx.x; i < n4; i += gridDim.x * 256) {
      const float4 v = ((const float4*)src)[i];
      short4 o = {bf16b(v.x), bf16b(v.y), bf16b(v.z), bf16b(v.w)};
      ((short4*)dst)[i] = o;
    }
  } else {
    const float* in;
    short* out;
    int R, Cc;
    switch (job) {
      case 4: in = w_A; out = wAT; R = C_; Cc = 64; break;
      case 5: in = a_A; out = aAT; R = C_; Cc = 64; break;
      case 6: in = v_A; out = vAT; R = C_; Cc = 64; break;
      case 7: in = g_A; out = gAT; R = C_; Cc = 128; break;
      case 8: in = w_B; out = wBT; R = 64; Cc = C_; break;
      case 9: in = a_B; out = aBT; R = 64; Cc = C_; break;
      case 10: in = v_B; out = vBT; R = 64; Cc = C_; break;
      default: in = g_B; out = gBT; R = 128; Cc = C_; break;
    }
    const int n = R * Cc;
    for (int i = blockIdx.x * 256 + threadIdx.x; i < n; i += gridDim.x * 256) {
      const int r = i / Cc, c = i % Cc;
      out[(size_t)c * R + r] = bf16b(in[i]);
    }
  }
}

// ---------------- kk prep: packed bf16 outputs ----------------
// 4 cols/lane, 16-lane group per (token,head); writes zb16/kr16 packed
// (z|b and k|r interleaved per 4-col group, 16B coalesced) + fp32 kout.
__global__ __launch_bounds__(256) void kkprep_k(
    const float* __restrict__ k0, const float* __restrict__ av_,
    const float* __restrict__ rr, const float* __restrict__ k_k,
    const float* __restrict__ k_a, float* __restrict__ kout,
    short* __restrict__ zb16, short* __restrict__ kr16) {
  const int tid = threadIdx.x;
  const int wv = tid >> 6, l = tid & 63;
  const int grp = l >> 4, g16 = l & 15;
  const size_t hid = (size_t)blockIdx.x * 16 + wv * 4 + grp;
  const int h = (int)(hid % H_);
  const size_t base = hid * 64 + g16 * 4;
  const int cc = h * 64 + g16 * 4;

  const float4 kv = *(const float4*)(k0 + base);
  const float4 aa = *(const float4*)(av_ + base);
  const float4 rv = *(const float4*)(rr + base);
  const float4 kkc = *(const float4*)(k_k + cc);
  const float4 kac = *(const float4*)(k_a + cc);

  const float kkx = kv.x * kkc.x, kky = kv.y * kkc.y, kkz = kv.z * kkc.z,
              kkw = kv.w * kkc.w;
  const float ssp = kkx * kkx + kky * kky + kkz * kkz + kkw * kkw;
  const float ss = row_sum16(ssp);
  const float denom = fmaxf(sqrtf(ss), 1e-12f);
  const float nx = kkx / denom, ny = kky / denom, nz = kkz / denom,
              nw = kkw / denom;

  bf16x8 zb = {bf16b(-nx), bf16b(-ny), bf16b(-nz), bf16b(-nw),
               bf16b(nx * aa.x), bf16b(ny * aa.y), bf16b(nz * aa.z),
               bf16b(nw * aa.w)};
  *(bf16x8*)(zb16 + hid * 128 + g16 * 8) = zb;

  const float knx = kv.x * (1.f + (aa.x - 1.f) * kac.x);
  const float kny = kv.y * (1.f + (aa.y - 1.f) * kac.y);
  const float knz = kv.z * (1.f + (aa.z - 1.f) * kac.z);
  const float knw = kv.w * (1.f + (aa.w - 1.f) * kac.w);
  bf16x8 kr = {bf16b(knx), bf16b(kny), bf16b(knz), bf16b(knw),
               bf16b(rv.x), bf16b(rv.y), bf16b(rv.z), bf16b(rv.w)};
  *(bf16x8*)(kr16 + hid * 128 + g16 * 8) = kr;

  *(float4*)(kout + base) = make_float4(knx, kny, knz, knw);
}

// ---------------- fused WKV-7 + stage2-g GEMM + v_first copy -------------
// 256 blocks x 256 threads. Blocks 0..191: recurrence (4 staged streams:
// w fp32, v fp32, zb16, kr16 -> 3 b128 + 1 b32 per step). Blocks 192..239:
// persistent stage2-g GEMM. Blocks 240..255: v_first copy.
#define CH 16
#define NC (T_ / CH)
__global__ __launch_bounds__(256) void wkv7f_k(
    const float* __restrict__ dd, const float* __restrict__ vv,
    const short* __restrict__ zb16, const short* __restrict__ kr16,
    float* __restrict__ yy, const short* __restrict__ h_g,
    const short* __restrict__ gBT, float* __restrict__ g_,
    const float4* __restrict__ cpsrc, float4* __restrict__ cpdst, int n4) {
  __shared__ __align__(16) char smem[2 * 16384];  // 32 KB
  const int blk = blockIdx.x;

  if (blk >= 240) {  // ---- copy role ----
    const int rb = blk - 240;
    for (int i = rb * 256 + threadIdx.x; i < n4; i += 16 * 256)
      cpdst[i] = cpsrc[i];
    return;
  }
  if (blk >= 192) {  // ---- stage2-g GEMM role (persistent, 8 tiles) ----
    short* As = (short*)smem;
    short* Bs = As + 128 * 32;
    const int rb = blk - 192;
    for (int it = 0; it < 8; ++it) {
      const int tile = rb + it * 48;  // 0..383
      gemm128_tile(h_g, gBT, g_, nullptr, B_ * T_, C_, 128, tile % 6,
                   tile / 6, EPI_NONE, nullptr, nullptr, nullptr, As, Bs);
    }
    return;
  }

  // ---- wkv7 role ----
  const int bh = blk % 48;
  const int rq = blk / 48;
  const int b = bh / H_, h = bh % H_;
  const int tid = threadIdx.x;
  const int wave = tid >> 6;
  const int l = tid & 63;
  const int l16 = l & 15;
  const int row = rq * 16 + wave * 4 + (l >> 4);
  const int cb = l16 * 4;
  const size_t btb = (size_t)b * T_;

  // fp32 streams (dd, vv): lane l covers step (l>>4), cols (l&15)*4
  const size_t gf0 = (btb + wave * 4 + (l >> 4)) * C_ + h * 64 + cb;
  // packed streams: per (token,head) 128 shorts; lane l -> group l&15
  const size_t gp0 =
      ((btb + wave * 4 + (l >> 4)) * H_ + h) * 128 + (size_t)(l & 15) * 8;

#define STAGE(BUF, GF, GP)                                                    \
  {                                                                           \
    char* Bb = smem + (BUF)*16384;                                            \
    GLD16(dd + (GF), (float*)Bb + wave * 256);                                \
    GLD16(vv + (GF), (float*)(Bb + 4096) + wave * 256);                       \
    GLD16(zb16 + (GP), (short*)(Bb + 8192) + wave * 512);                     \
    GLD16(kr16 + (GP), (short*)(Bb + 12288) + wave * 512);                    \
  }

#define LDSTEP(S_, TL_)                                                       \
  {                                                                           \
    Wf[S_] = *(const float4*)&Lw[(TL_)*64 + cb];                              \
    Vf[S_] = Lv[(TL_)*64 + row];                                              \
    ZB[S_] = *(const bf16x8*)&Lzb[(TL_)*128 + l16 * 8];                       \
    KR[S_] = *(const bf16x8*)&Lkr[(TL_)*128 + l16 * 8];                       \
  }

#define CHUNK_BODY(CIDX)                                                      \
  {                                                                           \
    float4 Wf[3];                                                             \
    float Vf[3];                                                              \
    bf16x8 ZB[3], KR[3];                                                      \
    LDSTEP(0, 0);                                                             \
    LDSTEP(1, 1);                                                             \
    _Pragma("unroll") for (int tl = 0; tl < CH; ++tl) {                       \
      const int sl = tl % 3;                                                  \
      if (tl + 2 < CH) { LDSTEP((tl + 2) % 3, tl + 2); }                      \
      const float4 w4 = Wf[sl];                                               \
      const float vi = Vf[sl];                                                \
      const bf16x8 zb = ZB[sl], kr = KR[sl];                                  \
      const float z0 = bf2f(zb[0]), z1 = bf2f(zb[1]), z2 = bf2f(zb[2]),       \
                  z3 = bf2f(zb[3]);                                           \
      const float b0 = bf2f(zb[4]), b1 = bf2f(zb[5]), b2 = bf2f(zb[6]),       \
                  b3 = bf2f(zb[7]);                                           \
      const float k0 = bf2f(kr[0]), k1 = bf2f(kr[1]), k2 = bf2f(kr[2]),       \
                  k3 = bf2f(kr[3]);                                           \
      const float r0 = bf2f(kr[4]), r1 = bf2f(kr[5]), r2 = bf2f(kr[6]),       \
                  r3 = bf2f(kr[7]);                                           \
      float sa = fmaf(S1, z1, S0 * z0) + fmaf(S3, z3, S2 * z2);               \
      sa = row_sum16(sa);                                                     \
      S0 = fmaf(S0, w4.x, fmaf(sa, b0, vi * k0));                             \
      S1 = fmaf(S1, w4.y, fmaf(sa, b1, vi * k1));                             \
      S2 = fmaf(S2, w4.z, fmaf(sa, b2, vi * k2));                             \
      S3 = fmaf(S3, w4.w, fmaf(sa, b3, vi * k3));                             \
      float yp = fmaf(S1, r1, S0 * r0) + fmaf(S3, r3, S2 * r2);               \
      yp = row_sum16(yp);                                                     \
      if (l16 == 0) yy[ybase + (size_t)((CIDX)*CH + tl) * C_] = yp;           \
    }                                                                         \
  }

  STAGE(0, gf0, gp0);
  __syncthreads();

  float S0 = 0.f, S1 = 0.f, S2 = 0.f, S3 = 0.f;
  size_t gf = gf0 + (size_t)CH * C_;
  size_t gp = gp0 + (size_t)CH * H_ * 128;
  const size_t ybase = btb * C_ + h * 64 + row;

  for (int c = 0; c < NC; c += 2) {
    STAGE(1, gf, gp);  // stage c+1
    gf += (size_t)CH * C_;
    gp += (size_t)CH * H_ * 128;
    {
      const float* Lw = (const float*)(smem);
      const float* Lv = (const float*)(smem + 4096);
      const short* Lzb = (const short*)(smem + 8192);
      const short* Lkr = (const short*)(smem + 12288);
      CHUNK_BODY(c)
    }
    __syncthreads();
    if (c + 2 < NC) STAGE(0, gf, gp);  // stage c+2
    gf += (size_t)CH * C_;
    gp += (size_t)CH * H_ * 128;
    {
      const float* Lw = (const float*)(smem + 16384);
      const float* Lv = (const float*)(smem + 16384 + 4096);
      const short* Lzb = (const short*)(smem + 16384 + 8192);
      const short* Lkr = (const short*)(smem + 16384 + 12288);
      CHUNK_BODY(c + 1)
    }
    __syncthreads();
  }
#undef STAGE
#undef LDSTEP
#undef CHUNK_BODY
}

// ---------------- GroupNorm + r_k term + g gating -> bf16 ----------------
__global__ __launch_bounds__(256) void gn_k(
    const float* __restrict__ y, const float* __restrict__ r,
    const float* __restrict__ k, const float* __restrict__ v,
    const float* __restrict__ g, const float* __restrict__ r_k,
    const float* __restrict__ ln_w, const float* __restrict__ ln_b,
    short* __restrict__ ymb) {
  const int wid = threadIdx.x >> 6;
  const int lane = threadIdx.x & 63;
  const size_t hid = (size_t)blockIdx.x * 4 + wid;
  const int h = (int)(hid % H_);
  const size_t idx = hid * 64 + lane;
  const int c = h * 64 + lane;

  const float yv = y[idx];
  const float mu = wave_sum64(yv) * (1.f / 64.f);
  const float sq = wave_sum64(yv * yv) * (1.f / 64.f);
  const float var = sq - mu * mu;
  float yn = (yv - mu) * rsqrtf(var + 0.00064f);
  yn = yn * ln_w[c] + ln_b[c];

  const float s = wave_sum64(r[idx] * k[idx] * r_k[c]);
  yn += s * v[idx];
  ymb[idx] = bf16b(yn * g[idx]);
}

// ---------------- host launcher ----------------
extern "C" void kernel_launch(void* const* d_in, const int* in_sizes, int n_in,
                              void* d_out, int out_size, void* d_ws,
                              size_t ws_size, hipStream_t stream) {
  const float* x       = (const float*)d_in[0];
  const float* v_first = (const float*)d_in[1];
  const float* lam_r   = (const float*)d_in[2];
  const float* lam_w   = (const float*)d_in[3];
  const float* lam_k   = (const float*)d_in[4];
  const float* lam_v   = (const float*)d_in[5];
  const float* lam_a   = (const float*)d_in[6];
  const float* lam_g   = (const float*)d_in[7];
  const float* w_miu   = (const float*)d_in[8];
  const float* w_A     = (const float*)d_in[9];
  const float* w_B     = (const float*)d_in[10];
  const float* a_miu   = (const float*)d_in[11];
  const float* a_A     = (const float*)d_in[12];
  const float* a_B     = (const float*)d_in[13];
  const float* v_miu   = (const float*)d_in[14];
  const float* v_A     = (const float*)d_in[15];
  const float* v_B     = (const float*)d_in[16];
  const float* g_A     = (const float*)d_in[17];
  const float* g_B     = (const float*)d_in[18];
  const float* k_k     = (const float*)d_in[19];
  const float* k_a     = (const float*)d_in[20];
  const float* r_k     = (const float*)d_in[21];
  const float* W_r     = (const float*)d_in[22];
  const float* W_k     = (const float*)d_in[23];
  const float* W_v     = (const float*)d_in[24];
  const float* W_o     = (const float*)d_in[25];
  const float* ln_w    = (const float*)d_in[26];
  const float* ln_b    = (const float*)d_in[27];

  const int M = B_ * T_;            // 8192
  const size_t S = (size_t)M * C_;  // 6291456

  float* ws   = (float*)d_ws;
  float* r_   = ws + 0 * S;
  float* kbuf = ws + 1 * S;
  float* vbuf = ws + 2 * S;
  float* dec_ = ws + 3 * S;
  float* a_   = ws + 4 * S;
  float* g_   = ws + 5 * S;
  float* z_   = ws + 6 * S;
  float* bb_  = ws + 7 * S;
  float* h_   = ws + 8 * S;                       // M*128 floats (stage-1 hs)
  short* wb   = (short*)(h_ + (size_t)M * 128);   // bf16 weight copies
  float* out  = (float*)d_out;

  const int WN = C_ * C_;  // 589824
  short* wrb = wb + 0 * (size_t)WN;
  short* wkb = wb + 1 * (size_t)WN;
  short* wvb = wb + 2 * (size_t)WN;
  short* wob = wb + 3 * (size_t)WN;
  short* wAT = wb + 4 * (size_t)WN;
  short* aAT = wAT + (size_t)C_ * 64;
  short* vAT = aAT + (size_t)C_ * 64;
  short* gAT = vAT + (size_t)C_ * 64;
  short* wBT = gAT + (size_t)C_ * 128;
  short* aBT = wBT + (size_t)C_ * 64;
  short* vBT = aBT + (size_t)C_ * 64;
  short* gBT = vBT + (size_t)C_ * 64;

  // bf16 aliases in dead fp32 slots
  short* xr  = (short*)dec_;          // consumed (big3) before dec_ written
  short* xk  = (short*)a_;            // consumed (big3) before a_ written
  short* xv  = (short*)g_;            // consumed (big3) before h_v written
  short* xw  = (short*)z_;            // consumed (s1) before kkprep writes zb16
  short* xa  = (short*)z_ + S;        // second half of z_ slot
  short* xg  = (short*)bb_;           // consumed (s1) before kkprep writes kr16
  short* vbuf16 = (short*)bb_ + S;    // second half of bb_ slot
  short* h_w = (short*)h_;            // M*64
  short* h_a = h_w + (size_t)M * 64;  // M*64
  short* h_g = h_a + (size_t)M * 64;  // M*128
  short* h_v = (short*)g_;            // g_ 1st half; s1 writes after xv dead,
                                      // s2-VMIX reads, dead before s2g writes g_
  short* zb16 = (short*)z_;           // packed z|b (kkprep out, wkv7 in)
  short* kr16 = (short*)bb_;          // packed k|r
  short* ymb = (short*)z_;            // gn out, after wkv7 consumed zb16

  // 1) weights prep (12 jobs, one launch)
  {
    dim3 blk(256), grid(576, 12);
    hipLaunchKernelGGL(wprep_k, grid, blk, 0, stream, W_r, W_k, W_v, W_o,
                       w_A, a_A, v_A, g_A, w_B, a_B, v_B, g_B, wrb, wkb, wvb,
                       wob, wAT, aAT, vAT, gAT, wBT, aBT, vBT, gBT);
  }
  // 2) mixed x -> bf16, all 6 lambdas
  {
    dim3 blk(256), grid((int)(S / 4 / 256));
    hipLaunchKernelGGL(mix6_k, grid, blk, 0, stream, x, lam_r, lam_k, lam_v,
                       lam_w, lam_a, lam_g, xr, xk, xv, xw, xa, xg);
  }
  // 3) big projections r/k/v (one launch; v dual-writes bf16)
  {
    dim3 blk(256), grid(18, M / 128);
    hipLaunchKernelGGL(big3_k, grid, blk, 0, stream, xr, xk, xv, wrb, wkb,
                       wvb, r_, kbuf, vbuf, vbuf16);
  }
  // 4) stage-1 low-rank projections (one launch, fused activations)
  {
    dim3 blk(256), grid(5, M / 128);
    hipLaunchKernelGGL(s1x4_k, grid, blk, 0, stream, xw, xa, xg, vbuf16, wAT,
                       aAT, gAT, vAT, h_w, h_a, h_g, h_v);
  }
  // 5) stage-2 expansions VMIX/WDECAY/SIGBIAS (one launch)
  {
    dim3 blk(256), grid(18, M / 128);
    hipLaunchKernelGGL(s2x3_k, grid, blk, 0, stream, h_v, h_w, h_a, vBT, wBT,
                       aBT, vbuf, dec_, a_, v_miu, w_miu, a_miu, v_first);
  }
  // 6) kk prep -> packed zb16/kr16 + fp32 kout
  {
    dim3 grid((B_ * T_ * H_) / 16), blk(256);
    hipLaunchKernelGGL(kkprep_k, grid, blk, 0, stream, kbuf, a_, r_, k_k,
                       k_a, kbuf, zb16, kr16);
  }
  // 7) fused recurrence + stage2-g GEMM + v_first copy (256 blocks)
  {
    dim3 grid(256), blk(256);
    hipLaunchKernelGGL(wkv7f_k, grid, blk, 0, stream, dec_, vbuf, zb16, kr16,
                       a_, h_g, gBT, g_, (const float4*)v_first,
                       (float4*)(out + S), (int)(S / 4));
  }
  // 8) groupnorm + rk-term + gate -> ymb
  {
    dim3 grid((B_ * T_ * H_) / 4), blk(256);
    hipLaunchKernelGGL(gn_k, grid, blk, 0, stream, a_, r_, kbuf, vbuf, g_, r_k,
                       ln_w, ln_b, ymb);
  }
  // 9) output projection
  {
    dim3 blk(256), grid(C_ / 128, M / 128);
    hipLaunchKernelGGL(outp_k, grid, blk, 0, stream, ymb, wob, out);
  }
}